// Round 15
// baseline (665.194 us; speedup 1.0000x reference)
//
#include <hip/hip_runtime.h>

#define BLK 256
#define BSHIFT 10
#define BSIZE 1024           // nodes per dst bucket (local index: 10 bits)
#define NSLICE 1024          // edge slices for hist/scatter
#define SCAN_T 512           // max K supported by single-block scan
#define KPAD 256             // max buckets (scan width in k_scatter)
#define EPT 8                // edges per thread per tile in scatter kernels
#define TILE (BLK * EPT)     // 2048 edges staged per tile
#define R2 8                 // sub-slices per bucket in within-bucket sort

typedef int iv4 __attribute__((ext_vector_type(4)));   // clang vector: nt-load legal

template <typename T>
__device__ __forceinline__ T ntload(const T* p) { return __builtin_nontemporal_load(p); }

__device__ __forceinline__ iv4 ntload4(const int* p) {
    return __builtin_nontemporal_load((const iv4*)p);
}

// ---------------- level-1: bucket by dst>>10 (no global atomics) ------------

__global__ void k_hist(const int* __restrict__ dst, int* __restrict__ partial,
                       int E, int chunk, int K) {
    extern __shared__ int cnt[];
    int s = blockIdx.x;
    for (int i = threadIdx.x; i < K; i += BLK) cnt[i] = 0;
    __syncthreads();
    int lo = s * chunk, hi = min(E, lo + chunk);
    for (int i = lo + threadIdx.x; i < hi; i += BLK)
        atomicAdd(&cnt[((unsigned)ntload(dst + i)) >> BSHIFT], 1);
    __syncthreads();
    int* prow = partial + (size_t)s * K;
    for (int i = threadIdx.x; i < K; i += BLK) prow[i] = cnt[i];
}

__global__ void __launch_bounds__(NSLICE) k_colscan(int* __restrict__ partial,
                                                    int* __restrict__ totals, int K) {
    __shared__ int sh[NSLICE];
    int k = blockIdx.x;
    int t = threadIdx.x;
    int v = partial[(size_t)t * K + k];
    sh[t] = v;
    __syncthreads();
    for (int off = 1; off < NSLICE; off <<= 1) {
        int u = (t >= off) ? sh[t - off] : 0;
        __syncthreads();
        sh[t] += u;
        __syncthreads();
    }
    partial[(size_t)t * K + k] = sh[t] - v;
    if (t == NSLICE - 1) totals[k] = sh[t];
}

__global__ void k_base(const int* __restrict__ totals, int* __restrict__ base, int K) {
    __shared__ int sh[SCAN_T];
    int t = threadIdx.x;
    int v = (t < K) ? totals[t] : 0;
    sh[t] = v;
    __syncthreads();
    for (int off = 1; off < SCAN_T; off <<= 1) {
        int u = (t >= off) ? sh[t - off] : 0;
        __syncthreads();
        sh[t] += u;
        __syncthreads();
    }
    if (t < K) base[t + 1] = sh[t];
    if (t == 0) base[0] = 0;
}

// tile counting-sort scatter: packed = (dst_local << sbits) | src
__global__ void __launch_bounds__(BLK) k_scatter(const int* __restrict__ src,
                                                 const int* __restrict__ dst,
                                                 const int* __restrict__ offs,
                                                 const int* __restrict__ base,
                                                 int* __restrict__ packed,
                                                 int E, int chunk, int K, int sbits) {
    __shared__ int cnt[KPAD];
    __shared__ int scn[KPAD];
    __shared__ int gstart[KPAD];
    __shared__ int cur[KPAD];
    __shared__ int stageval[TILE];
    __shared__ int stageaddr[TILE];
    int s = blockIdx.x;
    int tid = threadIdx.x;
    const int* orow = offs + (size_t)s * K;
    if (tid < K) cur[tid] = orow[tid] + base[tid];
    int lo = s * chunk, hi = min(E, lo + chunk);

    for (int tlo = lo; tlo < hi; tlo += TILE) {
        for (int k2 = tid; k2 < KPAD; k2 += BLK) cnt[k2] = 0;
        __syncthreads();

        int kk[EPT], rr[EPT], vv[EPT];
#pragma unroll
        for (int j = 0; j < EPT; ++j) {
            int i = tlo + j * BLK + tid;
            kk[j] = -1;
            if (i < hi) {
                int d = ntload(dst + i);
                int sc = ntload(src + i);
                kk[j] = ((unsigned)d) >> BSHIFT;
                vv[j] = ((d & (BSIZE - 1)) << sbits) | sc;
                rr[j] = atomicAdd(&cnt[kk[j]], 1);
            }
        }
        __syncthreads();

        int c = cnt[tid];
        scn[tid] = c;
        __syncthreads();
        for (int off = 1; off < KPAD; off <<= 1) {
            int u = (tid >= off) ? scn[tid - off] : 0;
            __syncthreads();
            scn[tid] += u;
            __syncthreads();
        }
        scn[tid] -= c;
        gstart[tid] = cur[tid];
        cur[tid] += c;
        __syncthreads();

#pragma unroll
        for (int j = 0; j < EPT; ++j) {
            if (kk[j] >= 0) {
                int idx = scn[kk[j]] + rr[j];
                stageval[idx]  = vv[j];
                stageaddr[idx] = gstart[kk[j]] + rr[j];
            }
        }
        __syncthreads();

        int tot = min(hi - tlo, TILE);
        for (int i2 = tid; i2 < tot; i2 += BLK)
            packed[stageaddr[i2]] = stageval[i2];
        __syncthreads();
    }
}

// ---------------- level-2: within-bucket sort, SLICE-MAJOR, single kernel ---
// block b = (k, r) owns contiguous window [s0,s1): pass A histograms the whole
// window + scans to cursors (+degN side-output), pass B tile-scatters. No
// cross-block deps -> k_hist2/k_scan2 eliminated.
__global__ void __launch_bounds__(BLK) k_scatter3(const int* __restrict__ packed,
                                                  const int* __restrict__ base,
                                                  int* __restrict__ packed2,
                                                  int* __restrict__ degN, int sbits) {
    __shared__ int cnt[BSIZE];
    __shared__ int cur[BSIZE];
    __shared__ int gstart[BSIZE];
    __shared__ int tsum[BLK];
    __shared__ int sval[TILE];
    __shared__ int sadr[TILE];
    int b = blockIdx.x;              // k*R2 + r
    int k = b / R2, r = b - k * R2;
    int tid = threadIdx.x;
    int lo = base[k], len = base[k + 1] - lo;
    int s0 = lo + (int)(((long long)len * r) / R2);
    int s1 = lo + (int)(((long long)len * (r + 1)) / R2);

    // ---- pass A: full-window histogram ----
    for (int i = tid; i < BSIZE; i += BLK) cnt[i] = 0;
    __syncthreads();
    {
        int a0 = min((s0 + 3) & ~3, s1);
        int a1 = max(s1 & ~3, a0);
        for (int i = s0 + tid; i < a0; i += BLK)
            atomicAdd(&cnt[((unsigned)ntload(packed + i)) >> sbits], 1);
        for (int i = a0 + 4 * tid; i < a1; i += 4 * BLK) {
            iv4 q = ntload4(packed + i);
            atomicAdd(&cnt[((unsigned)q.x) >> sbits], 1);
            atomicAdd(&cnt[((unsigned)q.y) >> sbits], 1);
            atomicAdd(&cnt[((unsigned)q.z) >> sbits], 1);
            atomicAdd(&cnt[((unsigned)q.w) >> sbits], 1);
        }
        for (int i = a1 + tid; i < s1; i += BLK)
            atomicAdd(&cnt[((unsigned)ntload(packed + i)) >> sbits], 1);
    }
    __syncthreads();

    // ---- scan 1024 bins (4/thread) -> write cursors; degree side-output ----
    int c0 = cnt[4 * tid], c1 = cnt[4 * tid + 1],
        c2 = cnt[4 * tid + 2], c3 = cnt[4 * tid + 3];
    int sum = c0 + c1 + c2 + c3;
    tsum[tid] = sum;
    __syncthreads();
    for (int off = 1; off < BLK; off <<= 1) {
        int u = (tid >= off) ? tsum[tid - off] : 0;
        __syncthreads();
        tsum[tid] += u;
        __syncthreads();
    }
    int run = s0 + tsum[tid] - sum;
    cur[4 * tid]     = run;
    cur[4 * tid + 1] = run + c0;
    cur[4 * tid + 2] = run + c0 + c1;
    cur[4 * tid + 3] = run + c0 + c1 + c2;
    int nb = (k << BSHIFT) + 4 * tid;
    if (c0) atomicAdd(&degN[nb], c0);
    if (c1) atomicAdd(&degN[nb + 1], c1);
    if (c2) atomicAdd(&degN[nb + 2], c2);
    if (c3) atomicAdd(&degN[nb + 3], c3);
    __syncthreads();

    // ---- pass B: tile counting-scatter (window is L2-hot after pass A) ----
    for (int tlo = s0; tlo < s1; tlo += TILE) {
        for (int i = tid; i < BSIZE; i += BLK) cnt[i] = 0;
        __syncthreads();

        int kk[EPT], rr[EPT], vv[EPT];
#pragma unroll
        for (int j = 0; j < EPT; ++j) {
            int i = tlo + j * BLK + tid;
            kk[j] = -1;
            if (i < s1) {
                int v = ntload(packed + i);
                vv[j] = v;
                kk[j] = ((unsigned)v) >> sbits;
                rr[j] = atomicAdd(&cnt[kk[j]], 1);
            }
        }
        __syncthreads();

        int d0 = cnt[4 * tid], d1 = cnt[4 * tid + 1],
            d2 = cnt[4 * tid + 2], d3 = cnt[4 * tid + 3];
        int dsum = d0 + d1 + d2 + d3;
        tsum[tid] = dsum;
        __syncthreads();
        for (int off = 1; off < BLK; off <<= 1) {
            int u = (tid >= off) ? tsum[tid - off] : 0;
            __syncthreads();
            tsum[tid] += u;
            __syncthreads();
        }
        int runb = tsum[tid] - dsum;  // exclusive
        gstart[4 * tid]     = cur[4 * tid];     cur[4 * tid]     += d0;
        gstart[4 * tid + 1] = cur[4 * tid + 1]; cur[4 * tid + 1] += d1;
        gstart[4 * tid + 2] = cur[4 * tid + 2]; cur[4 * tid + 2] += d2;
        gstart[4 * tid + 3] = cur[4 * tid + 3]; cur[4 * tid + 3] += d3;
        cnt[4 * tid]     = runb;
        cnt[4 * tid + 1] = runb + d0;
        cnt[4 * tid + 2] = runb + d0 + d1;
        cnt[4 * tid + 3] = runb + d0 + d1 + d2;
        __syncthreads();

#pragma unroll
        for (int j = 0; j < EPT; ++j) {
            if (kk[j] >= 0) {
                int idx = cnt[kk[j]] + rr[j];
                sval[idx] = vv[j];
                sadr[idx] = gstart[kk[j]] + rr[j];
            }
        }
        __syncthreads();

        int tot = min(s1 - tlo, TILE);
        for (int i2 = tid; i2 < tot; i2 += BLK)
            packed2[sadr[i2]] = sval[i2];
        __syncthreads();
    }
}

// ---------------- aggregation ----------------

// fallback degree kernel (unsorted path only)
__global__ void k_deg(const int* __restrict__ packed, const int* __restrict__ base,
                      int M, int* __restrict__ degpart, int sbits) {
    __shared__ int cnt[BSIZE];
    int b = blockIdx.x;
    int k = b / M, m = b - k * M;
    for (int i = threadIdx.x; i < BSIZE; i += BLK) cnt[i] = 0;
    __syncthreads();
    int lo = base[k], len = base[k + 1] - lo;
    int l0 = lo + (int)(((long long)len * m) / M);
    int l1 = lo + (int)(((long long)len * (m + 1)) / M);
    for (int i = l0 + threadIdx.x; i < l1; i += BLK)
        atomicAdd(&cnt[((unsigned)ntload(packed + i)) >> sbits], 1);
    __syncthreads();
    int* outp = degpart + (size_t)b * BSIZE;
    for (int i = threadIdx.x; i < BSIZE; i += BLK) outp[i] = cnt[i];
}

// sorted-edge agg: 16 consecutive edges/thread, register run-accumulation,
// LDS atomic only at run boundaries (~0.16/edge). No cross-lane ops.
__global__ void __launch_bounds__(BLK) k_agg3(const int* __restrict__ packed2,
                                              const int* __restrict__ base,
                                              int M, const float2* __restrict__ pin,
                                              float* __restrict__ partial,
                                              int sbits, int smask) {
    __shared__ float accx[BSIZE];
    __shared__ float accy[BSIZE];
    int b = blockIdx.x;
    int k = b / M, m = b - k * M;
    for (int i = threadIdx.x; i < BSIZE; i += BLK) { accx[i] = 0.f; accy[i] = 0.f; }
    __syncthreads();
    int lo = base[k], len = base[k + 1] - lo;
    int l0 = lo + (int)(((long long)len * m) / M);
    int l1 = lo + (int)(((long long)len * (m + 1)) / M);
    int a0 = min((l0 + 3) & ~3, l1);
    int a1 = a0 + (((l1 - a0) / (16 * BLK)) * (16 * BLK));

    for (int i = a0 + 16 * threadIdx.x; i < a1; i += 16 * BLK) {
        iv4 q0 = ntload4(packed2 + i);
        iv4 q1 = ntload4(packed2 + i + 4);
        iv4 q2 = ntload4(packed2 + i + 8);
        iv4 q3 = ntload4(packed2 + i + 12);
        unsigned v[16];
        v[0]=q0.x; v[1]=q0.y; v[2]=q0.z; v[3]=q0.w;
        v[4]=q1.x; v[5]=q1.y; v[6]=q1.z; v[7]=q1.w;
        v[8]=q2.x; v[9]=q2.y; v[10]=q2.z; v[11]=q2.w;
        v[12]=q3.x; v[13]=q3.y; v[14]=q3.z; v[15]=q3.w;
        float2 e[16];
#pragma unroll
        for (int j = 0; j < 16; ++j) e[j] = pin[v[j] & smask];  // 16 gathers in flight
        int curk = (int)(v[0] >> sbits);
        float ax = e[0].x, ay = e[0].y;
#pragma unroll
        for (int j = 1; j < 16; ++j) {
            int kj = (int)(v[j] >> sbits);
            if (kj == curk) { ax += e[j].x; ay += e[j].y; }
            else {
                atomicAdd(&accx[curk], ax);
                atomicAdd(&accy[curk], ay);
                curk = kj; ax = e[j].x; ay = e[j].y;
            }
        }
        atomicAdd(&accx[curk], ax);
        atomicAdd(&accy[curk], ay);
    }
    // remainder + head (scalar, direct atomic)
    for (int j = a1 + threadIdx.x; j < l1; j += BLK) {
        unsigned v = (unsigned)ntload(packed2 + j);
        float2 pv = pin[v & smask];
        int l = v >> sbits;
        atomicAdd(&accx[l], pv.x);
        atomicAdd(&accy[l], pv.y);
    }
    for (int j = l0 + threadIdx.x; j < a0; j += BLK) {
        unsigned v = (unsigned)ntload(packed2 + j);
        float2 pv = pin[v & smask];
        int l = v >> sbits;
        atomicAdd(&accx[l], pv.x);
        atomicAdd(&accy[l], pv.y);
    }
    __syncthreads();
    float* outp = partial + (size_t)b * (BSIZE * 2);
    for (int j = threadIdx.x * 2; j < BSIZE; j += BLK * 2) {
        float4 o = make_float4(accx[j], accy[j], accx[j + 1], accy[j + 1]);
        *(float4*)(outp + 2 * j) = o;
    }
}

// fallback: unsorted gather agg (4-wide) when ws too small for level-2
__global__ void __launch_bounds__(BLK) k_agg(const int* __restrict__ packed,
                                             const int* __restrict__ base,
                                             int M, const float2* __restrict__ pin,
                                             float* __restrict__ partial,
                                             int sbits, int smask) {
    __shared__ float accx[BSIZE];
    __shared__ float accy[BSIZE];
    int b = blockIdx.x;
    int k = b / M, m = b - k * M;
    for (int i = threadIdx.x; i < BSIZE; i += BLK) { accx[i] = 0.f; accy[i] = 0.f; }
    __syncthreads();
    int lo = base[k], len = base[k + 1] - lo;
    int l0 = lo + (int)(((long long)len * m) / M);
    int l1 = lo + (int)(((long long)len * (m + 1)) / M);
    int a0 = min((l0 + 3) & ~3, l1);
    int a1 = max(l1 & ~3, a0);
    for (int i = l0 + threadIdx.x; i < a0; i += BLK) {
        unsigned v = (unsigned)ntload(packed + i);
        float2 pv = pin[v & smask];
        int l = v >> sbits;
        atomicAdd(&accx[l], pv.x);
        atomicAdd(&accy[l], pv.y);
    }
    for (int i = a0 + 4 * threadIdx.x; i < a1; i += 4 * BLK) {
        iv4 q = ntload4(packed + i);
        unsigned v0 = q.x, v1 = q.y, v2 = q.z, v3 = q.w;
        float2 e0 = pin[v0 & smask];
        float2 e1 = pin[v1 & smask];
        float2 e2 = pin[v2 & smask];
        float2 e3 = pin[v3 & smask];
        int l0i = v0 >> sbits, l1i = v1 >> sbits, l2i = v2 >> sbits, l3i = v3 >> sbits;
        atomicAdd(&accx[l0i], e0.x); atomicAdd(&accy[l0i], e0.y);
        atomicAdd(&accx[l1i], e1.x); atomicAdd(&accy[l1i], e1.y);
        atomicAdd(&accx[l2i], e2.x); atomicAdd(&accy[l2i], e2.y);
        atomicAdd(&accx[l3i], e3.x); atomicAdd(&accy[l3i], e3.y);
    }
    for (int j = a1 + threadIdx.x; j < l1; j += BLK) {
        unsigned v = (unsigned)ntload(packed + j);
        float2 pv = pin[v & smask];
        int l = v >> sbits;
        atomicAdd(&accx[l], pv.x);
        atomicAdd(&accy[l], pv.y);
    }
    __syncthreads();
    float* outp = partial + (size_t)b * (BSIZE * 2);
    for (int j = threadIdx.x * 2; j < BSIZE; j += BLK * 2) {
        float4 o = make_float4(accx[j], accy[j], accx[j + 1], accy[j + 1]);
        *(float4*)(outp + 2 * j) = o;
    }
}

// ---------------- node epilogues ----------------

__global__ void k_node1c(const int* __restrict__ degN, const float* __restrict__ x,
                         const float* __restrict__ W1, float* __restrict__ dinv,
                         float2* __restrict__ p1, int N) {
    int i = blockIdx.x * BLK + threadIdx.x;
    if (i >= N) return;
    float di = rsqrtf((float)degN[i] + 1.0f);
    dinv[i] = di;
    float2 xv = ((const float2*)x)[i];
    float w00 = W1[0], w01 = W1[1], w10 = W1[2], w11 = W1[3];
    p1[i] = make_float2(di * (xv.x * w00 + xv.y * w10),
                        di * (xv.x * w01 + xv.y * w11));
}

__global__ void k_node1(const int* __restrict__ degpart, int M,
                        const float* __restrict__ x, const float* __restrict__ W1,
                        float* __restrict__ dinv, float2* __restrict__ p1, int N) {
    int i = blockIdx.x * BLK + threadIdx.x;
    if (i >= N) return;
    int k = i >> BSHIFT, l = i & (BSIZE - 1);
    int c = 0;
    for (int m = 0; m < M; ++m) c += degpart[((size_t)(k * M + m)) * BSIZE + l];
    float di = rsqrtf((float)c + 1.0f);
    dinv[i] = di;
    float2 xv = ((const float2*)x)[i];
    float w00 = W1[0], w01 = W1[1], w10 = W1[2], w11 = W1[3];
    p1[i] = make_float2(di * (xv.x * w00 + xv.y * w10),
                        di * (xv.x * w01 + xv.y * w11));
}

__global__ void k_node_mid(const float* __restrict__ partial, int M,
                           const float* __restrict__ dinv, const float2* __restrict__ pin,
                           const float* __restrict__ b, const float* __restrict__ W,
                           float2* __restrict__ pout, int N) {
    int i = blockIdx.x * BLK + threadIdx.x;
    if (i >= N) return;
    int k = i >> BSHIFT, l = i & (BSIZE - 1);
    float2 self = pin[i];
    float ax = self.x, ay = self.y;
    for (int m = 0; m < M; ++m) {
        const float* pp = partial + ((size_t)(k * M + m)) * (BSIZE * 2) + 2 * l;
        ax += pp[0]; ay += pp[1];
    }
    float di = dinv[i];
    float h0 = fmaxf(fmaf(di, ax, b[0]), 0.f);
    float h1 = fmaxf(fmaf(di, ay, b[1]), 0.f);
    float w00 = W[0], w01 = W[1], w10 = W[2], w11 = W[3];
    pout[i] = make_float2(di * (h0 * w00 + h1 * w10),
                          di * (h0 * w01 + h1 * w11));
}

__global__ void k_out_init(float* __restrict__ out, const float* __restrict__ br, int G) {
    int i = blockIdx.x * BLK + threadIdx.x;
    if (i < G) out[i] = br[0];
}

__global__ void k_node_final(const float* __restrict__ partial, int M,
                             const float* __restrict__ dinv, const float2* __restrict__ pin,
                             const float* __restrict__ b, const float* __restrict__ Wr,
                             const int* __restrict__ batch, float* __restrict__ out, int N) {
    int i = blockIdx.x * BLK + threadIdx.x;
    bool valid = i < N;
    float s = 0.f;
    int key = -1;
    if (valid) {
        int k = i >> BSHIFT, l = i & (BSIZE - 1);
        float2 self = pin[i];
        float ax = self.x, ay = self.y;
        for (int m = 0; m < M; ++m) {
            const float* pp = partial + ((size_t)(k * M + m)) * (BSIZE * 2) + 2 * l;
            ax += pp[0]; ay += pp[1];
        }
        float di = dinv[i];
        float h0 = fmaxf(fmaf(di, ax, b[0]), 0.f);
        float h1 = fmaxf(fmaf(di, ay, b[1]), 0.f);
        s = fmaf(h0, Wr[0], h1 * Wr[1]);
        key = batch[i];
    }
    int lane = threadIdx.x & 63;
    for (int off = 1; off < 64; off <<= 1) {
        float s2 = __shfl_down(s, off);
        int k2 = __shfl_down(key, off);
        if (lane + off < 64 && k2 == key) s += s2;
    }
    int kprev = __shfl_up(key, 1);
    if (valid && (lane == 0 || kprev != key)) unsafeAtomicAdd(&out[key], s);
}

// ---------------- launch ----------------

extern "C" void kernel_launch(void* const* d_in, const int* in_sizes, int n_in,
                              void* d_out, int out_size, void* d_ws, size_t ws_size,
                              hipStream_t stream) {
    const float* x    = (const float*)d_in[0];
    const int*   ei   = (const int*)d_in[1];
    const int*   batch= (const int*)d_in[2];
    const float* W1   = (const float*)d_in[3];
    const float* b1   = (const float*)d_in[4];
    const float* W2   = (const float*)d_in[5];
    const float* b2   = (const float*)d_in[6];
    const float* W3   = (const float*)d_in[7];
    const float* b3   = (const float*)d_in[8];
    const float* Wr   = (const float*)d_in[9];
    const float* br   = (const float*)d_in[10];
    float* out = (float*)d_out;

    int N = in_sizes[0] / 2;
    int E = in_sizes[1] / 2;
    int G = out_size;
    const int* src = ei;
    const int* dst = ei + E;

    int K = (N + BSIZE - 1) >> BSHIFT;
    if (K > KPAD) return;
    int S = NSLICE;
    int chunk = (E + S - 1) / S;

    int sbits = 1;
    while ((1 << sbits) < N) ++sbits;
    if (sbits + BSHIFT > 32) return;
    int smask = (1 << sbits) - 1;

    auto pad16 = [](size_t b) { return (b + 15) & ~(size_t)15; };
    size_t fixed = pad16((size_t)E * 4)                       // packed
                 + pad16((size_t)S * K * 4)                   // hpart
                 + pad16((size_t)(K + 1) * 4)                 // basep
                 + pad16((size_t)K * 4)                       // totals
                 + pad16((size_t)N * 4)                       // dinv
                 + 2 * pad16((size_t)N * 8);                  // pA, pB
    size_t lvl2 = pad16((size_t)E * 4)                        // packed2
                + pad16((size_t)K * BSIZE * 4);               // degN

    bool sorted = true;
    int M = 16;
    for (;;) {
        size_t need = fixed + pad16((size_t)K * M * BSIZE * 2 * 4) + (sorted ? lvl2 : 0);
        if (need <= ws_size) break;
        if (M > 4) { M >>= 1; continue; }
        if (sorted) { sorted = false; M = 16; continue; }
        if (M > 1) { M >>= 1; continue; }
        return;
    }

    char* w = (char*)d_ws;
    size_t off = 0;
    auto carve = [&](size_t bytes) { void* p = w + off; off += (bytes + 15) & ~(size_t)15; return p; };
    int*    packed  = (int*)carve((size_t)E * 4);
    int*    hpart   = (int*)carve((size_t)S * K * 4);
    int*    basep   = (int*)carve((size_t)(K + 1) * 4);
    int*    totals  = (int*)carve((size_t)K * 4);
    float*  aggpart = (float*)carve((size_t)K * M * BSIZE * 2 * 4);
    float*  dinv    = (float*)carve((size_t)N * 4);
    float2* pA      = (float2*)carve((size_t)N * 8);
    float2* pB      = (float2*)carve((size_t)N * 8);
    int*    packed2 = nullptr;
    int*    degN    = nullptr;
    if (sorted) {
        packed2 = (int*)carve((size_t)E * 4);
        degN    = (int*)carve((size_t)K * BSIZE * 4);
    }
    int* degpart = (int*)aggpart;            // fallback only: consumed before first agg

    int NB = (N + BLK - 1) / BLK;
    int GB = (G + BLK - 1) / BLK;
    size_t smemK = (size_t)K * 4;
    int KM = K * M;

    // level-1 bucket build
    k_hist   <<<S, BLK, smemK, stream>>>(dst, hpart, E, chunk, K);
    k_colscan<<<K, NSLICE, 0, stream>>>(hpart, totals, K);
    k_base   <<<1, SCAN_T, 0, stream>>>(totals, basep, K);
    k_scatter<<<S, BLK, 0, stream>>>(src, dst, hpart, basep, packed, E, chunk, K, sbits);

    if (sorted) {
        // level-2: merged hist+scan+scatter per window, degree side-output
        hipMemsetAsync(degN, 0, (size_t)K * BSIZE * 4, stream);
        k_scatter3<<<K * R2, BLK, 0, stream>>>(packed, basep, packed2, degN, sbits);
        k_node1c  <<<NB, BLK, 0, stream>>>(degN, x, W1, dinv, pA, N);

        k_agg3    <<<KM, BLK, 0, stream>>>(packed2, basep, M, pA, aggpart, sbits, smask);
        k_node_mid<<<NB, BLK, 0, stream>>>(aggpart, M, dinv, pA, b1, W2, pB, N);
        k_agg3    <<<KM, BLK, 0, stream>>>(packed2, basep, M, pB, aggpart, sbits, smask);
        k_node_mid<<<NB, BLK, 0, stream>>>(aggpart, M, dinv, pB, b2, W3, pA, N);
        k_agg3    <<<KM, BLK, 0, stream>>>(packed2, basep, M, pA, aggpart, sbits, smask);
    } else {
        k_deg     <<<KM, BLK, 0, stream>>>(packed, basep, M, degpart, sbits);
        k_node1   <<<NB, BLK, 0, stream>>>(degpart, M, x, W1, dinv, pA, N);
        k_agg     <<<KM, BLK, 0, stream>>>(packed, basep, M, pA, aggpart, sbits, smask);
        k_node_mid<<<NB, BLK, 0, stream>>>(aggpart, M, dinv, pA, b1, W2, pB, N);
        k_agg     <<<KM, BLK, 0, stream>>>(packed, basep, M, pB, aggpart, sbits, smask);
        k_node_mid<<<NB, BLK, 0, stream>>>(aggpart, M, dinv, pB, b2, W3, pA, N);
        k_agg     <<<KM, BLK, 0, stream>>>(packed, basep, M, pA, aggpart, sbits, smask);
    }

    k_out_init<<<GB, BLK, 0, stream>>>(out, br, G);
    k_node_final<<<NB, BLK, 0, stream>>>(aggpart, M, dinv, pA, b3, Wr, batch, out, N);
}

// Round 16
// 491.404 us; speedup vs baseline: 1.3537x; 1.3537x over previous
//
#include <hip/hip_runtime.h>

#define BLK 256
#define BSHIFT 8
#define BSIZE 256            // nodes per dst bucket == level-2 bins
#define NSLICE 1024          // edge slices for level-1 hist/scatter
#define SCAN_T 1024          // k_base scan width (K <= 1024)
#define KPAD 1024            // level-1 bin array size (K <= 1024)
#define EPT 8                // edges per thread per tile in scatter kernels
#define TILE (BLK * EPT)     // 2048 edges staged per tile

typedef int iv4 __attribute__((ext_vector_type(4)));

template <typename T>
__device__ __forceinline__ T ntload(const T* p) { return __builtin_nontemporal_load(p); }

__device__ __forceinline__ iv4 ntload4(const int* p) {
    return __builtin_nontemporal_load((const iv4*)p);
}

// DPP wave-sum (rocPRIM gfx9 sequence): result lands in lane 63.
template <int CTRL>
__device__ __forceinline__ float dpp_add(float v) {
    int t = __builtin_amdgcn_update_dpp(0, __float_as_int(v), CTRL, 0xf, 0xf, true);
    return v + __int_as_float(t);
}
__device__ __forceinline__ float wave_sum63(float v) {
    v = dpp_add<0x111>(v);   // row_shr:1
    v = dpp_add<0x112>(v);   // row_shr:2
    v = dpp_add<0x114>(v);   // row_shr:4
    v = dpp_add<0x118>(v);   // row_shr:8  -> lane15 of each row = row sum
    v = dpp_add<0x142>(v);   // row_bcast:15
    v = dpp_add<0x143>(v);   // row_bcast:31 -> lane63 = total
    return v;
}

// ---------------- level-1: bucket by dst>>8 (no global atomics) -------------

__global__ void k_hist(const int* __restrict__ dst, int* __restrict__ partial,
                       int E, int chunk, int K) {
    extern __shared__ int cnt[];
    int s = blockIdx.x;
    for (int i = threadIdx.x; i < K; i += BLK) cnt[i] = 0;
    __syncthreads();
    int lo = s * chunk, hi = min(E, lo + chunk);
    for (int i = lo + threadIdx.x; i < hi; i += BLK)
        atomicAdd(&cnt[((unsigned)ntload(dst + i)) >> BSHIFT], 1);
    __syncthreads();
    int* prow = partial + (size_t)s * K;
    for (int i = threadIdx.x; i < K; i += BLK) prow[i] = cnt[i];
}

__global__ void __launch_bounds__(NSLICE) k_colscan(int* __restrict__ partial,
                                                    int* __restrict__ totals, int K) {
    __shared__ int sh[NSLICE];
    int k = blockIdx.x;
    int t = threadIdx.x;
    int v = partial[(size_t)t * K + k];
    sh[t] = v;
    __syncthreads();
    for (int off = 1; off < NSLICE; off <<= 1) {
        int u = (t >= off) ? sh[t - off] : 0;
        __syncthreads();
        sh[t] += u;
        __syncthreads();
    }
    partial[(size_t)t * K + k] = sh[t] - v;
    if (t == NSLICE - 1) totals[k] = sh[t];
}

__global__ void __launch_bounds__(SCAN_T) k_base(const int* __restrict__ totals,
                                                 int* __restrict__ base, int K) {
    __shared__ int sh[SCAN_T];
    int t = threadIdx.x;
    int v = (t < K) ? totals[t] : 0;
    sh[t] = v;
    __syncthreads();
    for (int off = 1; off < SCAN_T; off <<= 1) {
        int u = (t >= off) ? sh[t - off] : 0;
        __syncthreads();
        sh[t] += u;
        __syncthreads();
    }
    if (t < K) base[t + 1] = sh[t];
    if (t == 0) base[0] = 0;
}

// tile counting-sort scatter into buckets: packed = (dst_local << sbits) | src
__global__ void __launch_bounds__(BLK) k_scatter(const int* __restrict__ src,
                                                 const int* __restrict__ dst,
                                                 const int* __restrict__ offs,
                                                 const int* __restrict__ base,
                                                 int* __restrict__ packed,
                                                 int E, int chunk, int K, int sbits) {
    __shared__ int cnt[KPAD];
    __shared__ int cur[KPAD];
    __shared__ int gstart[KPAD];
    __shared__ int tsum[BLK];
    __shared__ int sval[TILE];
    __shared__ int sadr[TILE];
    int s = blockIdx.x;
    int tid = threadIdx.x;
    const int* orow = offs + (size_t)s * K;
    for (int t = tid; t < KPAD; t += BLK) cur[t] = (t < K) ? orow[t] + base[t] : 0;
    int lo = s * chunk, hi = min(E, lo + chunk);

    for (int tlo = lo; tlo < hi; tlo += TILE) {
        for (int t = tid; t < KPAD; t += BLK) cnt[t] = 0;
        __syncthreads();

        int kk[EPT], rr[EPT], vv[EPT];
#pragma unroll
        for (int j = 0; j < EPT; ++j) {
            int i = tlo + j * BLK + tid;
            kk[j] = -1;
            if (i < hi) {
                int d = ntload(dst + i);
                int sc = ntload(src + i);
                kk[j] = ((unsigned)d) >> BSHIFT;
                vv[j] = ((d & (BSIZE - 1)) << sbits) | sc;
                rr[j] = atomicAdd(&cnt[kk[j]], 1);
            }
        }
        __syncthreads();

        // 1024-bin scan: 4 bins/thread + 256-wide block scan
        int c0 = cnt[4 * tid], c1 = cnt[4 * tid + 1],
            c2 = cnt[4 * tid + 2], c3 = cnt[4 * tid + 3];
        int sum = c0 + c1 + c2 + c3;
        tsum[tid] = sum;
        __syncthreads();
        for (int off = 1; off < BLK; off <<= 1) {
            int u = (tid >= off) ? tsum[tid - off] : 0;
            __syncthreads();
            tsum[tid] += u;
            __syncthreads();
        }
        int runb = tsum[tid] - sum;
        gstart[4 * tid]     = cur[4 * tid];     cur[4 * tid]     += c0;
        gstart[4 * tid + 1] = cur[4 * tid + 1]; cur[4 * tid + 1] += c1;
        gstart[4 * tid + 2] = cur[4 * tid + 2]; cur[4 * tid + 2] += c2;
        gstart[4 * tid + 3] = cur[4 * tid + 3]; cur[4 * tid + 3] += c3;
        cnt[4 * tid]     = runb;
        cnt[4 * tid + 1] = runb + c0;
        cnt[4 * tid + 2] = runb + c0 + c1;
        cnt[4 * tid + 3] = runb + c0 + c1 + c2;
        __syncthreads();

#pragma unroll
        for (int j = 0; j < EPT; ++j) {
            if (kk[j] >= 0) {
                int idx = cnt[kk[j]] + rr[j];
                sval[idx] = vv[j];
                sadr[idx] = gstart[kk[j]] + rr[j];
            }
        }
        __syncthreads();

        int tot = min(hi - tlo, TILE);
        for (int i2 = tid; i2 < tot; i2 += BLK)
            packed[sadr[i2]] = sval[i2];
        __syncthreads();
    }
}

// ---------------- level-2: full per-bucket sort by dst_local -> CSR ---------
// block k sorts its whole bucket (contiguous window); emits rowptr as side
// output. Per-node edge runs become fully contiguous.
__global__ void __launch_bounds__(BLK) k_sort2(const int* __restrict__ packed,
                                               const int* __restrict__ base,
                                               int* __restrict__ packed2,
                                               int* __restrict__ rowptr,
                                               int sbits, int K, int E) {
    __shared__ int cnt[BSIZE];
    __shared__ int cur[BSIZE];
    __shared__ int gstart[BSIZE];
    __shared__ int sc[BLK];
    __shared__ int sval[TILE];
    __shared__ int sadr[TILE];
    int k = blockIdx.x;
    int tid = threadIdx.x;               // BLK == BSIZE == 256
    int lo = base[k], hi = base[k + 1];

    // pass A: full-bucket histogram
    cnt[tid] = 0;
    __syncthreads();
    {
        int a0 = min((lo + 3) & ~3, hi);
        int a1 = max(hi & ~3, a0);
        for (int i = lo + tid; i < a0; i += BLK)
            atomicAdd(&cnt[((unsigned)ntload(packed + i)) >> sbits], 1);
        for (int i = a0 + 4 * tid; i < a1; i += 4 * BLK) {
            iv4 q = ntload4(packed + i);
            atomicAdd(&cnt[((unsigned)q.x) >> sbits], 1);
            atomicAdd(&cnt[((unsigned)q.y) >> sbits], 1);
            atomicAdd(&cnt[((unsigned)q.z) >> sbits], 1);
            atomicAdd(&cnt[((unsigned)q.w) >> sbits], 1);
        }
        for (int i = a1 + tid; i < hi; i += BLK)
            atomicAdd(&cnt[((unsigned)ntload(packed + i)) >> sbits], 1);
    }
    __syncthreads();

    // scan 256 bins -> cursors + rowptr
    int c = cnt[tid];
    sc[tid] = c;
    __syncthreads();
    for (int off = 1; off < BLK; off <<= 1) {
        int u = (tid >= off) ? sc[tid - off] : 0;
        __syncthreads();
        sc[tid] += u;
        __syncthreads();
    }
    int start = lo + sc[tid] - c;
    cur[tid] = start;
    rowptr[(k << BSHIFT) + tid] = start;
    if (k == K - 1 && tid == 0) rowptr[K << BSHIFT] = E;
    __syncthreads();

    // pass B: tile counting-scatter into [lo,hi)
    for (int tlo = lo; tlo < hi; tlo += TILE) {
        cnt[tid] = 0;
        __syncthreads();

        int kk[EPT], rr[EPT], vv[EPT];
#pragma unroll
        for (int j = 0; j < EPT; ++j) {
            int i = tlo + j * BLK + tid;
            kk[j] = -1;
            if (i < hi) {
                int v = ntload(packed + i);
                vv[j] = v;
                kk[j] = ((unsigned)v) >> sbits;
                rr[j] = atomicAdd(&cnt[kk[j]], 1);
            }
        }
        __syncthreads();

        int d = cnt[tid];
        sc[tid] = d;
        __syncthreads();
        for (int off = 1; off < BLK; off <<= 1) {
            int u = (tid >= off) ? sc[tid - off] : 0;
            __syncthreads();
            sc[tid] += u;
            __syncthreads();
        }
        int excl = sc[tid] - d;
        gstart[tid] = cur[tid];
        cur[tid] += d;
        cnt[tid] = excl;
        __syncthreads();

#pragma unroll
        for (int j = 0; j < EPT; ++j) {
            if (kk[j] >= 0) {
                int idx = cnt[kk[j]] + rr[j];
                sval[idx] = vv[j];
                sadr[idx] = gstart[kk[j]] + rr[j];
            }
        }
        __syncthreads();

        int tot = min(hi - tlo, TILE);
        for (int i2 = tid; i2 < tot; i2 += BLK)
            packed2[sadr[i2]] = sval[i2];
        __syncthreads();
    }
}

// ---------------- fused aggregation: wave-per-node over CSR -----------------
// coalesced edge loads + gather + DPP wave-sum (no LDS ops, no atomics),
// epilogue (relu + 2x2 matmul + dinv scale) fused -> writes next layer's p.
__global__ void __launch_bounds__(BLK) k_agg4(const int* __restrict__ edges,
                                              const int* __restrict__ rowptr,
                                              const float* __restrict__ dinv,
                                              const float2* __restrict__ pin,
                                              const float* __restrict__ b,
                                              const float* __restrict__ W,
                                              float2* __restrict__ pout,
                                              int N, int smask) {
    int wid = threadIdx.x >> 6, lane = threadIdx.x & 63;
    int n = blockIdx.x * 4 + wid;
    if (n >= N) return;
    int e0 = rowptr[n], e1 = rowptr[n + 1];
    float sx = 0.f, sy = 0.f;
    for (int i = e0 + lane; i < e1; i += 64) {
        float2 e = pin[((unsigned)edges[i]) & smask];
        sx += e.x;
        sy += e.y;
    }
    sx = wave_sum63(sx);
    sy = wave_sum63(sy);
    if (lane == 63) {
        float di = dinv[n];
        float2 self = pin[n];
        float ax = sx + self.x, ay = sy + self.y;
        float h0 = fmaxf(fmaf(di, ax, b[0]), 0.f);
        float h1 = fmaxf(fmaf(di, ay, b[1]), 0.f);
        pout[n] = make_float2(di * (h0 * W[0] + h1 * W[2]),
                              di * (h0 * W[1] + h1 * W[3]));
    }
}

// final layer: epilogue ends at s = h @ Wr -> sv[n]
__global__ void __launch_bounds__(BLK) k_agg4f(const int* __restrict__ edges,
                                               const int* __restrict__ rowptr,
                                               const float* __restrict__ dinv,
                                               const float2* __restrict__ pin,
                                               const float* __restrict__ b,
                                               const float* __restrict__ Wr,
                                               float* __restrict__ sv,
                                               int N, int smask) {
    int wid = threadIdx.x >> 6, lane = threadIdx.x & 63;
    int n = blockIdx.x * 4 + wid;
    if (n >= N) return;
    int e0 = rowptr[n], e1 = rowptr[n + 1];
    float sx = 0.f, sy = 0.f;
    for (int i = e0 + lane; i < e1; i += 64) {
        float2 e = pin[((unsigned)edges[i]) & smask];
        sx += e.x;
        sy += e.y;
    }
    sx = wave_sum63(sx);
    sy = wave_sum63(sy);
    if (lane == 63) {
        float di = dinv[n];
        float2 self = pin[n];
        float ax = sx + self.x, ay = sy + self.y;
        float h0 = fmaxf(fmaf(di, ax, b[0]), 0.f);
        float h1 = fmaxf(fmaf(di, ay, b[1]), 0.f);
        sv[n] = fmaf(h0, Wr[0], h1 * Wr[1]);
    }
}

// ---------------- node prologue / pooling ----------------

__global__ void k_node1(const int* __restrict__ rowptr, const float* __restrict__ x,
                        const float* __restrict__ W1, float* __restrict__ dinv,
                        float2* __restrict__ p1, int N) {
    int i = blockIdx.x * BLK + threadIdx.x;
    if (i >= N) return;
    int deg = rowptr[i + 1] - rowptr[i];
    float di = rsqrtf((float)deg + 1.0f);
    dinv[i] = di;
    float2 xv = ((const float2*)x)[i];
    float w00 = W1[0], w01 = W1[1], w10 = W1[2], w11 = W1[3];
    p1[i] = make_float2(di * (xv.x * w00 + xv.y * w10),
                        di * (xv.x * w01 + xv.y * w11));
}

__global__ void k_out_init(float* __restrict__ out, const float* __restrict__ br, int G) {
    int i = blockIdx.x * BLK + threadIdx.x;
    if (i < G) out[i] = br[0];
}

__global__ void k_pool(const float* __restrict__ sv, const int* __restrict__ batch,
                       float* __restrict__ out, int N) {
    int i = blockIdx.x * BLK + threadIdx.x;
    bool valid = i < N;
    float s = valid ? sv[i] : 0.f;
    int key = valid ? batch[i] : -1;
    int lane = threadIdx.x & 63;
    for (int off = 1; off < 64; off <<= 1) {
        float s2 = __shfl_down(s, off);
        int k2 = __shfl_down(key, off);
        if (lane + off < 64 && k2 == key) s += s2;
    }
    int kprev = __shfl_up(key, 1);
    if (valid && (lane == 0 || kprev != key)) unsafeAtomicAdd(&out[key], s);
}

// ---------------- launch ----------------

extern "C" void kernel_launch(void* const* d_in, const int* in_sizes, int n_in,
                              void* d_out, int out_size, void* d_ws, size_t ws_size,
                              hipStream_t stream) {
    const float* x    = (const float*)d_in[0];
    const int*   ei   = (const int*)d_in[1];
    const int*   batch= (const int*)d_in[2];
    const float* W1   = (const float*)d_in[3];
    const float* b1   = (const float*)d_in[4];
    const float* W2   = (const float*)d_in[5];
    const float* b2   = (const float*)d_in[6];
    const float* W3   = (const float*)d_in[7];
    const float* b3   = (const float*)d_in[8];
    const float* Wr   = (const float*)d_in[9];
    const float* br   = (const float*)d_in[10];
    float* out = (float*)d_out;

    int N = in_sizes[0] / 2;
    int E = in_sizes[1] / 2;
    int G = out_size;
    const int* src = ei;
    const int* dst = ei + E;

    int K = (N + BSIZE - 1) >> BSHIFT;
    if (K > KPAD) return;                       // shape guard
    int S = NSLICE;
    int chunk = (E + S - 1) / S;

    int sbits = 1;
    while ((1 << sbits) < N) ++sbits;           // 18 for N=200000
    if (sbits + BSHIFT > 31) return;
    int smask = (1 << sbits) - 1;

    auto pad16 = [](size_t b) { return (b + 15) & ~(size_t)15; };
    size_t need = pad16((size_t)E * 4)                 // packed
                + pad16((size_t)S * K * 4)             // hpart
                + pad16((size_t)(K + 1) * 4)           // basep
                + pad16((size_t)K * 4)                 // totals
                + pad16((size_t)E * 4)                 // packed2
                + pad16(((size_t)K * BSIZE + 1) * 4)   // rowptr
                + pad16((size_t)N * 4)                 // dinv
                + 2 * pad16((size_t)N * 8)             // pA, pB
                + pad16((size_t)N * 4);                // sv
    if (need > ws_size) return;

    char* w = (char*)d_ws;
    size_t off = 0;
    auto carve = [&](size_t bytes) { void* p = w + off; off += (bytes + 15) & ~(size_t)15; return p; };
    int*    packed  = (int*)carve((size_t)E * 4);
    int*    hpart   = (int*)carve((size_t)S * K * 4);
    int*    basep   = (int*)carve((size_t)(K + 1) * 4);
    int*    totals  = (int*)carve((size_t)K * 4);
    int*    packed2 = (int*)carve((size_t)E * 4);
    int*    rowptr  = (int*)carve(((size_t)K * BSIZE + 1) * 4);
    float*  dinv    = (float*)carve((size_t)N * 4);
    float2* pA      = (float2*)carve((size_t)N * 8);
    float2* pB      = (float2*)carve((size_t)N * 8);
    float*  sv      = (float*)carve((size_t)N * 4);

    int NB = (N + BLK - 1) / BLK;
    int GB = (G + BLK - 1) / BLK;
    int WB = (N + 3) / 4;                       // wave-per-node grid
    size_t smemK = (size_t)K * 4;

    // level-1: bucket by dst>>8
    k_hist   <<<S, BLK, smemK, stream>>>(dst, hpart, E, chunk, K);
    k_colscan<<<K, NSLICE, 0, stream>>>(hpart, totals, K);
    k_base   <<<1, SCAN_T, 0, stream>>>(totals, basep, K);
    k_scatter<<<S, BLK, 0, stream>>>(src, dst, hpart, basep, packed, E, chunk, K, sbits);

    // level-2: full per-bucket sort -> CSR (rowptr side-output)
    k_sort2  <<<K, BLK, 0, stream>>>(packed, basep, packed2, rowptr, sbits, K, E);

    // dinv + p1
    k_node1  <<<NB, BLK, 0, stream>>>(rowptr, x, W1, dinv, pA, N);

    // fused layers (agg + relu + next matmul)
    k_agg4   <<<WB, BLK, 0, stream>>>(packed2, rowptr, dinv, pA, b1, W2, pB, N, smask);
    k_agg4   <<<WB, BLK, 0, stream>>>(packed2, rowptr, dinv, pB, b2, W3, pA, N, smask);
    k_agg4f  <<<WB, BLK, 0, stream>>>(packed2, rowptr, dinv, pA, b3, Wr, sv, N, smask);

    // pool + readout
    k_out_init<<<GB, BLK, 0, stream>>>(out, br, G);
    k_pool    <<<NB, BLK, 0, stream>>>(sv, batch, out, N);
}

// Round 17
// 418.514 us; speedup vs baseline: 1.5894x; 1.1742x over previous
//
#include <hip/hip_runtime.h>

#define BLK 256
#define BLK2 1024            // wide blocks for level-1 hist/scatter
#define BSHIFT 8
#define BSIZE 256            // nodes per dst bucket == level-2 bins
#define NSLICE 256           // edge slices for level-1 (long runs -> low write amp)
#define SCAN_T 1024          // k_base scan width (K <= 1024)
#define KPAD 1024            // level-1 bin array size (K <= 1024)
#define EPT 8                // edges per thread per tile
#define TILE (BLK * EPT)     // level-2 staging tile (2048)
#define TILE2 (BLK2 * EPT)   // level-1 staging tile (8192)

typedef int iv4 __attribute__((ext_vector_type(4)));

template <typename T>
__device__ __forceinline__ T ntload(const T* p) { return __builtin_nontemporal_load(p); }

__device__ __forceinline__ iv4 ntload4(const int* p) {
    return __builtin_nontemporal_load((const iv4*)p);
}

// DPP wave-sum (rocPRIM gfx9 sequence): result lands in lane 63.
template <int CTRL>
__device__ __forceinline__ float dpp_add(float v) {
    int t = __builtin_amdgcn_update_dpp(0, __float_as_int(v), CTRL, 0xf, 0xf, true);
    return v + __int_as_float(t);
}
__device__ __forceinline__ float wave_sum63(float v) {
    v = dpp_add<0x111>(v);   // row_shr:1
    v = dpp_add<0x112>(v);   // row_shr:2
    v = dpp_add<0x114>(v);   // row_shr:4
    v = dpp_add<0x118>(v);   // row_shr:8
    v = dpp_add<0x142>(v);   // row_bcast:15
    v = dpp_add<0x143>(v);   // row_bcast:31 -> lane63 = total
    return v;
}

// ---------------- level-1: bucket by dst>>8 (no global atomics) -------------

__global__ void __launch_bounds__(BLK2) k_hist(const int* __restrict__ dst,
                                               int* __restrict__ partial,
                                               int E, int chunk, int K) {
    extern __shared__ int cnt[];
    int s = blockIdx.x;
    for (int i = threadIdx.x; i < K; i += BLK2) cnt[i] = 0;
    __syncthreads();
    int lo = s * chunk, hi = min(E, lo + chunk);
    int a0 = min((lo + 3) & ~3, hi);
    int a1 = max(hi & ~3, a0);
    for (int i = lo + threadIdx.x; i < a0; i += BLK2)
        atomicAdd(&cnt[((unsigned)ntload(dst + i)) >> BSHIFT], 1);
    for (int i = a0 + 4 * threadIdx.x; i < a1; i += 4 * BLK2) {
        iv4 q = ntload4(dst + i);
        atomicAdd(&cnt[((unsigned)q.x) >> BSHIFT], 1);
        atomicAdd(&cnt[((unsigned)q.y) >> BSHIFT], 1);
        atomicAdd(&cnt[((unsigned)q.z) >> BSHIFT], 1);
        atomicAdd(&cnt[((unsigned)q.w) >> BSHIFT], 1);
    }
    for (int i = a1 + threadIdx.x; i < hi; i += BLK2)
        atomicAdd(&cnt[((unsigned)ntload(dst + i)) >> BSHIFT], 1);
    __syncthreads();
    int* prow = partial + (size_t)s * K;
    for (int i = threadIdx.x; i < K; i += BLK2) prow[i] = cnt[i];
}

__global__ void __launch_bounds__(NSLICE) k_colscan(int* __restrict__ partial,
                                                    int* __restrict__ totals, int K) {
    __shared__ int sh[NSLICE];
    int k = blockIdx.x;
    int t = threadIdx.x;                  // blockDim.x == NSLICE
    int v = partial[(size_t)t * K + k];
    sh[t] = v;
    __syncthreads();
    for (int off = 1; off < NSLICE; off <<= 1) {
        int u = (t >= off) ? sh[t - off] : 0;
        __syncthreads();
        sh[t] += u;
        __syncthreads();
    }
    partial[(size_t)t * K + k] = sh[t] - v;
    if (t == NSLICE - 1) totals[k] = sh[t];
}

__global__ void __launch_bounds__(SCAN_T) k_base(const int* __restrict__ totals,
                                                 int* __restrict__ base, int K) {
    __shared__ int sh[SCAN_T];
    int t = threadIdx.x;
    int v = (t < K) ? totals[t] : 0;
    sh[t] = v;
    __syncthreads();
    for (int off = 1; off < SCAN_T; off <<= 1) {
        int u = (t >= off) ? sh[t - off] : 0;
        __syncthreads();
        sh[t] += u;
        __syncthreads();
    }
    if (t < K) base[t + 1] = sh[t];
    if (t == 0) base[0] = 0;
}

// 1024-thread tile counting-sort scatter: packed = (dst_local << sbits) | src
__global__ void __launch_bounds__(BLK2) k_scatter(const int* __restrict__ src,
                                                  const int* __restrict__ dst,
                                                  const int* __restrict__ offs,
                                                  const int* __restrict__ base,
                                                  int* __restrict__ packed,
                                                  int E, int chunk, int K, int sbits) {
    __shared__ int cnt[KPAD];
    __shared__ int cur[KPAD];
    __shared__ int gstart[KPAD];
    __shared__ int tsum[KPAD];
    __shared__ int sval[TILE2];
    __shared__ int sadr[TILE2];
    int s = blockIdx.x;
    int tid = threadIdx.x;
    const int* orow = offs + (size_t)s * K;
    cur[tid] = (tid < K) ? orow[tid] + base[tid] : 0;
    int lo = s * chunk, hi = min(E, lo + chunk);

    for (int tlo = lo; tlo < hi; tlo += TILE2) {
        cnt[tid] = 0;
        __syncthreads();

        int kk[EPT], rr[EPT], vv[EPT];
#pragma unroll
        for (int j = 0; j < EPT; ++j) {
            int i = tlo + j * BLK2 + tid;
            kk[j] = -1;
            if (i < hi) {
                int d = ntload(dst + i);
                int sc = ntload(src + i);
                kk[j] = ((unsigned)d) >> BSHIFT;
                vv[j] = ((d & (BSIZE - 1)) << sbits) | sc;
                rr[j] = atomicAdd(&cnt[kk[j]], 1);
            }
        }
        __syncthreads();

        // 1024-wide direct bin scan (1 bin/thread)
        int c = cnt[tid];
        tsum[tid] = c;
        __syncthreads();
        for (int off = 1; off < KPAD; off <<= 1) {
            int u = (tid >= off) ? tsum[tid - off] : 0;
            __syncthreads();
            tsum[tid] += u;
            __syncthreads();
        }
        int excl = tsum[tid] - c;
        gstart[tid] = cur[tid];
        cur[tid] += c;
        cnt[tid] = excl;
        __syncthreads();

#pragma unroll
        for (int j = 0; j < EPT; ++j) {
            if (kk[j] >= 0) {
                int idx = cnt[kk[j]] + rr[j];
                sval[idx] = vv[j];
                sadr[idx] = gstart[kk[j]] + rr[j];
            }
        }
        __syncthreads();

        int tot = min(hi - tlo, TILE2);
        for (int i2 = tid; i2 < tot; i2 += BLK2)
            packed[sadr[i2]] = sval[i2];
        __syncthreads();
    }
}

// ---------------- level-2: full per-bucket sort by dst_local -> CSR ---------

__global__ void __launch_bounds__(BLK) k_sort2(const int* __restrict__ packed,
                                               const int* __restrict__ base,
                                               int* __restrict__ packed2,
                                               int* __restrict__ rowptr,
                                               int sbits, int K, int E) {
    __shared__ int cnt[BSIZE];
    __shared__ int cur[BSIZE];
    __shared__ int gstart[BSIZE];
    __shared__ int sc[BLK];
    __shared__ int sval[TILE];
    __shared__ int sadr[TILE];
    int k = blockIdx.x;
    int tid = threadIdx.x;               // BLK == BSIZE == 256
    int lo = base[k], hi = base[k + 1];

    // pass A: full-bucket histogram
    cnt[tid] = 0;
    __syncthreads();
    {
        int a0 = min((lo + 3) & ~3, hi);
        int a1 = max(hi & ~3, a0);
        for (int i = lo + tid; i < a0; i += BLK)
            atomicAdd(&cnt[((unsigned)ntload(packed + i)) >> sbits], 1);
        for (int i = a0 + 4 * tid; i < a1; i += 4 * BLK) {
            iv4 q = ntload4(packed + i);
            atomicAdd(&cnt[((unsigned)q.x) >> sbits], 1);
            atomicAdd(&cnt[((unsigned)q.y) >> sbits], 1);
            atomicAdd(&cnt[((unsigned)q.z) >> sbits], 1);
            atomicAdd(&cnt[((unsigned)q.w) >> sbits], 1);
        }
        for (int i = a1 + tid; i < hi; i += BLK)
            atomicAdd(&cnt[((unsigned)ntload(packed + i)) >> sbits], 1);
    }
    __syncthreads();

    // scan 256 bins -> cursors + rowptr
    int c = cnt[tid];
    sc[tid] = c;
    __syncthreads();
    for (int off = 1; off < BLK; off <<= 1) {
        int u = (tid >= off) ? sc[tid - off] : 0;
        __syncthreads();
        sc[tid] += u;
        __syncthreads();
    }
    int start = lo + sc[tid] - c;
    cur[tid] = start;
    rowptr[(k << BSHIFT) + tid] = start;
    if (k == K - 1 && tid == 0) rowptr[K << BSHIFT] = E;
    __syncthreads();

    // pass B: tile counting-scatter into [lo,hi)
    for (int tlo = lo; tlo < hi; tlo += TILE) {
        cnt[tid] = 0;
        __syncthreads();

        int kk[EPT], rr[EPT], vv[EPT];
#pragma unroll
        for (int j = 0; j < EPT; ++j) {
            int i = tlo + j * BLK + tid;
            kk[j] = -1;
            if (i < hi) {
                int v = ntload(packed + i);
                vv[j] = v;
                kk[j] = ((unsigned)v) >> sbits;
                rr[j] = atomicAdd(&cnt[kk[j]], 1);
            }
        }
        __syncthreads();

        int d = cnt[tid];
        sc[tid] = d;
        __syncthreads();
        for (int off = 1; off < BLK; off <<= 1) {
            int u = (tid >= off) ? sc[tid - off] : 0;
            __syncthreads();
            sc[tid] += u;
            __syncthreads();
        }
        int excl = sc[tid] - d;
        gstart[tid] = cur[tid];
        cur[tid] += d;
        cnt[tid] = excl;
        __syncthreads();

#pragma unroll
        for (int j = 0; j < EPT; ++j) {
            if (kk[j] >= 0) {
                int idx = cnt[kk[j]] + rr[j];
                sval[idx] = vv[j];
                sadr[idx] = gstart[kk[j]] + rr[j];
            }
        }
        __syncthreads();

        int tot = min(hi - tlo, TILE);
        for (int i2 = tid; i2 < tot; i2 += BLK)
            packed2[sadr[i2]] = sval[i2];
        __syncthreads();
    }
}

// ---------------- fused aggregation: wave-per-node over CSR -----------------

__global__ void __launch_bounds__(BLK) k_agg4(const int* __restrict__ edges,
                                              const int* __restrict__ rowptr,
                                              const float* __restrict__ dinv,
                                              const float2* __restrict__ pin,
                                              const float* __restrict__ b,
                                              const float* __restrict__ W,
                                              float2* __restrict__ pout,
                                              int N, int smask) {
    int wid = threadIdx.x >> 6, lane = threadIdx.x & 63;
    int n = blockIdx.x * 4 + wid;
    if (n >= N) return;
    int e0 = rowptr[n], e1 = rowptr[n + 1];
    float sx = 0.f, sy = 0.f;
    for (int i = e0 + lane; i < e1; i += 64) {
        float2 e = pin[((unsigned)edges[i]) & smask];
        sx += e.x;
        sy += e.y;
    }
    sx = wave_sum63(sx);
    sy = wave_sum63(sy);
    if (lane == 63) {
        float di = dinv[n];
        float2 self = pin[n];
        float ax = sx + self.x, ay = sy + self.y;
        float h0 = fmaxf(fmaf(di, ax, b[0]), 0.f);
        float h1 = fmaxf(fmaf(di, ay, b[1]), 0.f);
        pout[n] = make_float2(di * (h0 * W[0] + h1 * W[2]),
                              di * (h0 * W[1] + h1 * W[3]));
    }
}

__global__ void __launch_bounds__(BLK) k_agg4f(const int* __restrict__ edges,
                                               const int* __restrict__ rowptr,
                                               const float* __restrict__ dinv,
                                               const float2* __restrict__ pin,
                                               const float* __restrict__ b,
                                               const float* __restrict__ Wr,
                                               float* __restrict__ sv,
                                               int N, int smask) {
    int wid = threadIdx.x >> 6, lane = threadIdx.x & 63;
    int n = blockIdx.x * 4 + wid;
    if (n >= N) return;
    int e0 = rowptr[n], e1 = rowptr[n + 1];
    float sx = 0.f, sy = 0.f;
    for (int i = e0 + lane; i < e1; i += 64) {
        float2 e = pin[((unsigned)edges[i]) & smask];
        sx += e.x;
        sy += e.y;
    }
    sx = wave_sum63(sx);
    sy = wave_sum63(sy);
    if (lane == 63) {
        float di = dinv[n];
        float2 self = pin[n];
        float ax = sx + self.x, ay = sy + self.y;
        float h0 = fmaxf(fmaf(di, ax, b[0]), 0.f);
        float h1 = fmaxf(fmaf(di, ay, b[1]), 0.f);
        sv[n] = fmaf(h0, Wr[0], h1 * Wr[1]);
    }
}

// ---------------- node prologue / pooling ----------------

__global__ void k_node1(const int* __restrict__ rowptr, const float* __restrict__ x,
                        const float* __restrict__ W1, float* __restrict__ dinv,
                        float2* __restrict__ p1, int N) {
    int i = blockIdx.x * BLK + threadIdx.x;
    if (i >= N) return;
    int deg = rowptr[i + 1] - rowptr[i];
    float di = rsqrtf((float)deg + 1.0f);
    dinv[i] = di;
    float2 xv = ((const float2*)x)[i];
    float w00 = W1[0], w01 = W1[1], w10 = W1[2], w11 = W1[3];
    p1[i] = make_float2(di * (xv.x * w00 + xv.y * w10),
                        di * (xv.x * w01 + xv.y * w11));
}

__global__ void k_out_init(float* __restrict__ out, const float* __restrict__ br, int G) {
    int i = blockIdx.x * BLK + threadIdx.x;
    if (i < G) out[i] = br[0];
}

__global__ void k_pool(const float* __restrict__ sv, const int* __restrict__ batch,
                       float* __restrict__ out, int N) {
    int i = blockIdx.x * BLK + threadIdx.x;
    bool valid = i < N;
    float s = valid ? sv[i] : 0.f;
    int key = valid ? batch[i] : -1;
    int lane = threadIdx.x & 63;
    for (int off = 1; off < 64; off <<= 1) {
        float s2 = __shfl_down(s, off);
        int k2 = __shfl_down(key, off);
        if (lane + off < 64 && k2 == key) s += s2;
    }
    int kprev = __shfl_up(key, 1);
    if (valid && (lane == 0 || kprev != key)) unsafeAtomicAdd(&out[key], s);
}

// ---------------- launch ----------------

extern "C" void kernel_launch(void* const* d_in, const int* in_sizes, int n_in,
                              void* d_out, int out_size, void* d_ws, size_t ws_size,
                              hipStream_t stream) {
    const float* x    = (const float*)d_in[0];
    const int*   ei   = (const int*)d_in[1];
    const int*   batch= (const int*)d_in[2];
    const float* W1   = (const float*)d_in[3];
    const float* b1   = (const float*)d_in[4];
    const float* W2   = (const float*)d_in[5];
    const float* b2   = (const float*)d_in[6];
    const float* W3   = (const float*)d_in[7];
    const float* b3   = (const float*)d_in[8];
    const float* Wr   = (const float*)d_in[9];
    const float* br   = (const float*)d_in[10];
    float* out = (float*)d_out;

    int N = in_sizes[0] / 2;
    int E = in_sizes[1] / 2;
    int G = out_size;
    const int* src = ei;
    const int* dst = ei + E;

    int K = (N + BSIZE - 1) >> BSHIFT;
    if (K > KPAD) return;                       // shape guard
    int S = NSLICE;
    int chunk = (E + S - 1) / S;

    int sbits = 1;
    while ((1 << sbits) < N) ++sbits;           // 18 for N=200000
    if (sbits + BSHIFT > 31) return;
    int smask = (1 << sbits) - 1;

    auto pad16 = [](size_t b) { return (b + 15) & ~(size_t)15; };
    size_t need = pad16((size_t)E * 4)                 // packed
                + pad16((size_t)S * K * 4)             // hpart
                + pad16((size_t)(K + 1) * 4)           // basep
                + pad16((size_t)K * 4)                 // totals
                + pad16((size_t)E * 4)                 // packed2
                + pad16(((size_t)K * BSIZE + 1) * 4)   // rowptr
                + pad16((size_t)N * 4)                 // dinv
                + 2 * pad16((size_t)N * 8)             // pA, pB
                + pad16((size_t)N * 4);                // sv
    if (need > ws_size) return;

    char* w = (char*)d_ws;
    size_t off = 0;
    auto carve = [&](size_t bytes) { void* p = w + off; off += (bytes + 15) & ~(size_t)15; return p; };
    int*    packed  = (int*)carve((size_t)E * 4);
    int*    hpart   = (int*)carve((size_t)S * K * 4);
    int*    basep   = (int*)carve((size_t)(K + 1) * 4);
    int*    totals  = (int*)carve((size_t)K * 4);
    int*    packed2 = (int*)carve((size_t)E * 4);
    int*    rowptr  = (int*)carve(((size_t)K * BSIZE + 1) * 4);
    float*  dinv    = (float*)carve((size_t)N * 4);
    float2* pA      = (float2*)carve((size_t)N * 8);
    float2* pB      = (float2*)carve((size_t)N * 8);
    float*  sv      = (float*)carve((size_t)N * 4);

    int NB = (N + BLK - 1) / BLK;
    int GB = (G + BLK - 1) / BLK;
    int WB = (N + 3) / 4;                       // wave-per-node grid
    size_t smemK = (size_t)K * 4;

    // level-1: bucket by dst>>8 (256 slices, 1024-thread blocks)
    k_hist   <<<S, BLK2, smemK, stream>>>(dst, hpart, E, chunk, K);
    k_colscan<<<K, NSLICE, 0, stream>>>(hpart, totals, K);
    k_base   <<<1, SCAN_T, 0, stream>>>(totals, basep, K);
    k_scatter<<<S, BLK2, 0, stream>>>(src, dst, hpart, basep, packed, E, chunk, K, sbits);

    // level-2: full per-bucket sort -> CSR (rowptr side-output)
    k_sort2  <<<K, BLK, 0, stream>>>(packed, basep, packed2, rowptr, sbits, K, E);

    // dinv + p1
    k_node1  <<<NB, BLK, 0, stream>>>(rowptr, x, W1, dinv, pA, N);

    // fused layers (agg + relu + next matmul)
    k_agg4   <<<WB, BLK, 0, stream>>>(packed2, rowptr, dinv, pA, b1, W2, pB, N, smask);
    k_agg4   <<<WB, BLK, 0, stream>>>(packed2, rowptr, dinv, pB, b2, W3, pA, N, smask);
    k_agg4f  <<<WB, BLK, 0, stream>>>(packed2, rowptr, dinv, pA, b3, Wr, sv, N, smask);

    // pool + readout
    k_out_init<<<GB, BLK, 0, stream>>>(out, br, G);
    k_pool    <<<NB, BLK, 0, stream>>>(sv, batch, out, N);
}

// Round 18
// 365.184 us; speedup vs baseline: 1.8215x; 1.1460x over previous
//
#include <hip/hip_runtime.h>

#define BLK 256
#define BLK2 1024            // wide blocks for level-1 hist/scatter
#define BSHIFT 8
#define BSIZE 256            // nodes per dst bucket == level-2 bins
#define NSLICE 256           // edge slices for level-1 (long runs -> low write amp)
#define SCAN_T 1024          // k_base scan width (K <= 1024)
#define KPAD 1024            // level-1 bin array size (K <= 1024)
#define EPT 8                // edges per thread per tile
#define TILE2 (BLK2 * EPT)   // level-1 staging tile (8192)
#define S2BLK 1024           // k_sort2 block size
#define S2CAP 18432          // max edges per bucket staged in LDS (72 KB)
#define S2MAXJ 18            // S2CAP / S2BLK

typedef int iv4 __attribute__((ext_vector_type(4)));

template <typename T>
__device__ __forceinline__ T ntload(const T* p) { return __builtin_nontemporal_load(p); }

__device__ __forceinline__ iv4 ntload4(const int* p) {
    return __builtin_nontemporal_load((const iv4*)p);
}

// DPP wave-sum (rocPRIM gfx9 sequence): result lands in lane 63.
template <int CTRL>
__device__ __forceinline__ float dpp_add(float v) {
    int t = __builtin_amdgcn_update_dpp(0, __float_as_int(v), CTRL, 0xf, 0xf, true);
    return v + __int_as_float(t);
}
__device__ __forceinline__ float wave_sum63(float v) {
    v = dpp_add<0x111>(v);   // row_shr:1
    v = dpp_add<0x112>(v);   // row_shr:2
    v = dpp_add<0x114>(v);   // row_shr:4
    v = dpp_add<0x118>(v);   // row_shr:8
    v = dpp_add<0x142>(v);   // row_bcast:15
    v = dpp_add<0x143>(v);   // row_bcast:31 -> lane63 = total
    return v;
}

// ---------------- level-1: bucket by dst>>8 (no global atomics) -------------

__global__ void __launch_bounds__(BLK2) k_hist(const int* __restrict__ dst,
                                               int* __restrict__ partial,
                                               int E, int chunk, int K) {
    extern __shared__ int cnt[];
    int s = blockIdx.x;
    for (int i = threadIdx.x; i < K; i += BLK2) cnt[i] = 0;
    __syncthreads();
    int lo = s * chunk, hi = min(E, lo + chunk);
    int a0 = min((lo + 3) & ~3, hi);
    int a1 = max(hi & ~3, a0);
    for (int i = lo + threadIdx.x; i < a0; i += BLK2)
        atomicAdd(&cnt[((unsigned)ntload(dst + i)) >> BSHIFT], 1);
    for (int i = a0 + 4 * threadIdx.x; i < a1; i += 4 * BLK2) {
        iv4 q = ntload4(dst + i);
        atomicAdd(&cnt[((unsigned)q.x) >> BSHIFT], 1);
        atomicAdd(&cnt[((unsigned)q.y) >> BSHIFT], 1);
        atomicAdd(&cnt[((unsigned)q.z) >> BSHIFT], 1);
        atomicAdd(&cnt[((unsigned)q.w) >> BSHIFT], 1);
    }
    for (int i = a1 + threadIdx.x; i < hi; i += BLK2)
        atomicAdd(&cnt[((unsigned)ntload(dst + i)) >> BSHIFT], 1);
    __syncthreads();
    int* prow = partial + (size_t)s * K;
    for (int i = threadIdx.x; i < K; i += BLK2) prow[i] = cnt[i];
}

__global__ void __launch_bounds__(NSLICE) k_colscan(int* __restrict__ partial,
                                                    int* __restrict__ totals, int K) {
    __shared__ int sh[NSLICE];
    int k = blockIdx.x;
    int t = threadIdx.x;                  // blockDim.x == NSLICE
    int v = partial[(size_t)t * K + k];
    sh[t] = v;
    __syncthreads();
    for (int off = 1; off < NSLICE; off <<= 1) {
        int u = (t >= off) ? sh[t - off] : 0;
        __syncthreads();
        sh[t] += u;
        __syncthreads();
    }
    partial[(size_t)t * K + k] = sh[t] - v;
    if (t == NSLICE - 1) totals[k] = sh[t];
}

__global__ void __launch_bounds__(SCAN_T) k_base(const int* __restrict__ totals,
                                                 int* __restrict__ base, int K) {
    __shared__ int sh[SCAN_T];
    int t = threadIdx.x;
    int v = (t < K) ? totals[t] : 0;
    sh[t] = v;
    __syncthreads();
    for (int off = 1; off < SCAN_T; off <<= 1) {
        int u = (t >= off) ? sh[t - off] : 0;
        __syncthreads();
        sh[t] += u;
        __syncthreads();
    }
    if (t < K) base[t + 1] = sh[t];
    if (t == 0) base[0] = 0;
}

// 1024-thread tile counting-sort scatter: packed = (dst_local << sbits) | src
__global__ void __launch_bounds__(BLK2) k_scatter(const int* __restrict__ src,
                                                  const int* __restrict__ dst,
                                                  const int* __restrict__ offs,
                                                  const int* __restrict__ base,
                                                  int* __restrict__ packed,
                                                  int E, int chunk, int K, int sbits) {
    __shared__ int cnt[KPAD];
    __shared__ int cur[KPAD];
    __shared__ int gstart[KPAD];
    __shared__ int tsum[KPAD];
    __shared__ int sval[TILE2];
    __shared__ int sadr[TILE2];
    int s = blockIdx.x;
    int tid = threadIdx.x;
    const int* orow = offs + (size_t)s * K;
    cur[tid] = (tid < K) ? orow[tid] + base[tid] : 0;
    int lo = s * chunk, hi = min(E, lo + chunk);

    for (int tlo = lo; tlo < hi; tlo += TILE2) {
        cnt[tid] = 0;
        __syncthreads();

        int kk[EPT], rr[EPT], vv[EPT];
#pragma unroll
        for (int j = 0; j < EPT; ++j) {
            int i = tlo + j * BLK2 + tid;
            kk[j] = -1;
            if (i < hi) {
                int d = ntload(dst + i);
                int sc = ntload(src + i);
                kk[j] = ((unsigned)d) >> BSHIFT;
                vv[j] = ((d & (BSIZE - 1)) << sbits) | sc;
                rr[j] = atomicAdd(&cnt[kk[j]], 1);
            }
        }
        __syncthreads();

        // 1024-wide direct bin scan (1 bin/thread)
        int c = cnt[tid];
        tsum[tid] = c;
        __syncthreads();
        for (int off = 1; off < KPAD; off <<= 1) {
            int u = (tid >= off) ? tsum[tid - off] : 0;
            __syncthreads();
            tsum[tid] += u;
            __syncthreads();
        }
        int excl = tsum[tid] - c;
        gstart[tid] = cur[tid];
        cur[tid] += c;
        cnt[tid] = excl;
        __syncthreads();

#pragma unroll
        for (int j = 0; j < EPT; ++j) {
            if (kk[j] >= 0) {
                int idx = cnt[kk[j]] + rr[j];
                sval[idx] = vv[j];
                sadr[idx] = gstart[kk[j]] + rr[j];
            }
        }
        __syncthreads();

        int tot = min(hi - tlo, TILE2);
        for (int i2 = tid; i2 < tot; i2 += BLK2)
            packed[sadr[i2]] = sval[i2];
        __syncthreads();
    }
}

// ---------------- level-2: per-bucket LDS-staged sort -> CSR ----------------
// One 1024-thread block per bucket. Single global read (edges -> registers,
// LDS histogram+rank), scan, scatter into LDS staging, coalesced nt-store out.
__global__ void __launch_bounds__(S2BLK) k_sort2(const int* __restrict__ packed,
                                                 const int* __restrict__ base,
                                                 int* __restrict__ packed2,
                                                 int* __restrict__ rowptr,
                                                 int sbits, int K, int E) {
    __shared__ int cnt[BSIZE];
    __shared__ int sc[BSIZE];
    __shared__ int startsh[BSIZE];
    __shared__ int cur[BSIZE];
    extern __shared__ int sorted[];      // S2CAP ints (72 KB)
    int k = blockIdx.x;
    int tid = threadIdx.x;
    int lo = base[k], hi = base[k + 1];
    int len = hi - lo;
    bool fits = (len <= S2CAP);          // block-uniform

    if (tid < BSIZE) cnt[tid] = 0;
    __syncthreads();

    int v[S2MAXJ], r[S2MAXJ];
    if (fits) {
        // load whole bucket to regs + LDS histogram with rank capture
#pragma unroll
        for (int j = 0; j < S2MAXJ; ++j) {
            int i = lo + j * S2BLK + tid;
            r[j] = -1;
            if (i < hi) {
                v[j] = ntload(packed + i);
                r[j] = atomicAdd(&cnt[((unsigned)v[j]) >> sbits], 1);
            }
        }
    } else {
        // rare fallback: histogram from global
        for (int i = lo + tid; i < hi; i += S2BLK)
            atomicAdd(&cnt[((unsigned)ntload(packed + i)) >> sbits], 1);
    }
    __syncthreads();

    // scan 256 bins (first 256 threads active; all threads hit barriers)
    if (tid < BSIZE) sc[tid] = cnt[tid];
    __syncthreads();
    for (int off = 1; off < BSIZE; off <<= 1) {
        int u = 0;
        if (tid < BSIZE && tid >= off) u = sc[tid - off];
        __syncthreads();
        if (tid < BSIZE) sc[tid] += u;
        __syncthreads();
    }
    if (tid < BSIZE) {
        int st = sc[tid] - cnt[tid];     // exclusive (bucket-local)
        startsh[tid] = st;
        cur[tid] = lo + st;
        rowptr[(k << BSHIFT) + tid] = lo + st;
    }
    if (k == K - 1 && tid == 0) rowptr[K << BSHIFT] = E;
    __syncthreads();

    if (fits) {
        // scatter into LDS staging
#pragma unroll
        for (int j = 0; j < S2MAXJ; ++j) {
            if (r[j] >= 0)
                sorted[startsh[((unsigned)v[j]) >> sbits] + r[j]] = v[j];
        }
        __syncthreads();
        // coalesced linear write-out
        for (int i = tid; i < len; i += S2BLK)
            __builtin_nontemporal_store(sorted[i], packed2 + lo + i);
    } else {
        // rare fallback: direct global scatter (arrival order within bin)
        for (int i = lo + tid; i < hi; i += S2BLK) {
            int val = ntload(packed + i);
            int pos = atomicAdd(&cur[((unsigned)val) >> sbits], 1);
            packed2[pos] = val;
        }
    }
}

// ---------------- fused aggregation: wave-per-node over CSR -----------------

__global__ void __launch_bounds__(BLK) k_agg4(const int* __restrict__ edges,
                                              const int* __restrict__ rowptr,
                                              const float* __restrict__ dinv,
                                              const float2* __restrict__ pin,
                                              const float* __restrict__ b,
                                              const float* __restrict__ W,
                                              float2* __restrict__ pout,
                                              int N, int smask) {
    int wid = threadIdx.x >> 6, lane = threadIdx.x & 63;
    int n = blockIdx.x * 4 + wid;
    if (n >= N) return;
    int e0 = rowptr[n], e1 = rowptr[n + 1];
    float sx = 0.f, sy = 0.f;
    for (int i = e0 + lane; i < e1; i += 64) {
        float2 e = pin[((unsigned)edges[i]) & smask];
        sx += e.x;
        sy += e.y;
    }
    sx = wave_sum63(sx);
    sy = wave_sum63(sy);
    if (lane == 63) {
        float di = dinv[n];
        float2 self = pin[n];
        float ax = sx + self.x, ay = sy + self.y;
        float h0 = fmaxf(fmaf(di, ax, b[0]), 0.f);
        float h1 = fmaxf(fmaf(di, ay, b[1]), 0.f);
        pout[n] = make_float2(di * (h0 * W[0] + h1 * W[2]),
                              di * (h0 * W[1] + h1 * W[3]));
    }
}

__global__ void __launch_bounds__(BLK) k_agg4f(const int* __restrict__ edges,
                                               const int* __restrict__ rowptr,
                                               const float* __restrict__ dinv,
                                               const float2* __restrict__ pin,
                                               const float* __restrict__ b,
                                               const float* __restrict__ Wr,
                                               float* __restrict__ sv,
                                               int N, int smask) {
    int wid = threadIdx.x >> 6, lane = threadIdx.x & 63;
    int n = blockIdx.x * 4 + wid;
    if (n >= N) return;
    int e0 = rowptr[n], e1 = rowptr[n + 1];
    float sx = 0.f, sy = 0.f;
    for (int i = e0 + lane; i < e1; i += 64) {
        float2 e = pin[((unsigned)edges[i]) & smask];
        sx += e.x;
        sy += e.y;
    }
    sx = wave_sum63(sx);
    sy = wave_sum63(sy);
    if (lane == 63) {
        float di = dinv[n];
        float2 self = pin[n];
        float ax = sx + self.x, ay = sy + self.y;
        float h0 = fmaxf(fmaf(di, ax, b[0]), 0.f);
        float h1 = fmaxf(fmaf(di, ay, b[1]), 0.f);
        sv[n] = fmaf(h0, Wr[0], h1 * Wr[1]);
    }
}

// ---------------- node prologue / pooling ----------------

__global__ void k_node1(const int* __restrict__ rowptr, const float* __restrict__ x,
                        const float* __restrict__ W1, float* __restrict__ dinv,
                        float2* __restrict__ p1, int N) {
    int i = blockIdx.x * BLK + threadIdx.x;
    if (i >= N) return;
    int deg = rowptr[i + 1] - rowptr[i];
    float di = rsqrtf((float)deg + 1.0f);
    dinv[i] = di;
    float2 xv = ((const float2*)x)[i];
    float w00 = W1[0], w01 = W1[1], w10 = W1[2], w11 = W1[3];
    p1[i] = make_float2(di * (xv.x * w00 + xv.y * w10),
                        di * (xv.x * w01 + xv.y * w11));
}

__global__ void k_out_init(float* __restrict__ out, const float* __restrict__ br, int G) {
    int i = blockIdx.x * BLK + threadIdx.x;
    if (i < G) out[i] = br[0];
}

__global__ void k_pool(const float* __restrict__ sv, const int* __restrict__ batch,
                       float* __restrict__ out, int N) {
    int i = blockIdx.x * BLK + threadIdx.x;
    bool valid = i < N;
    float s = valid ? sv[i] : 0.f;
    int key = valid ? batch[i] : -1;
    int lane = threadIdx.x & 63;
    for (int off = 1; off < 64; off <<= 1) {
        float s2 = __shfl_down(s, off);
        int k2 = __shfl_down(key, off);
        if (lane + off < 64 && k2 == key) s += s2;
    }
    int kprev = __shfl_up(key, 1);
    if (valid && (lane == 0 || kprev != key)) unsafeAtomicAdd(&out[key], s);
}

// ---------------- launch ----------------

extern "C" void kernel_launch(void* const* d_in, const int* in_sizes, int n_in,
                              void* d_out, int out_size, void* d_ws, size_t ws_size,
                              hipStream_t stream) {
    const float* x    = (const float*)d_in[0];
    const int*   ei   = (const int*)d_in[1];
    const int*   batch= (const int*)d_in[2];
    const float* W1   = (const float*)d_in[3];
    const float* b1   = (const float*)d_in[4];
    const float* W2   = (const float*)d_in[5];
    const float* b2   = (const float*)d_in[6];
    const float* W3   = (const float*)d_in[7];
    const float* b3   = (const float*)d_in[8];
    const float* Wr   = (const float*)d_in[9];
    const float* br   = (const float*)d_in[10];
    float* out = (float*)d_out;

    int N = in_sizes[0] / 2;
    int E = in_sizes[1] / 2;
    int G = out_size;
    const int* src = ei;
    const int* dst = ei + E;

    int K = (N + BSIZE - 1) >> BSHIFT;
    if (K > KPAD) return;                       // shape guard
    int S = NSLICE;
    int chunk = (E + S - 1) / S;

    int sbits = 1;
    while ((1 << sbits) < N) ++sbits;           // 18 for N=200000
    if (sbits + BSHIFT > 31) return;
    int smask = (1 << sbits) - 1;

    auto pad16 = [](size_t b) { return (b + 15) & ~(size_t)15; };
    size_t need = pad16((size_t)E * 4)                 // packed
                + pad16((size_t)S * K * 4)             // hpart
                + pad16((size_t)(K + 1) * 4)           // basep
                + pad16((size_t)K * 4)                 // totals
                + pad16((size_t)E * 4)                 // packed2
                + pad16(((size_t)K * BSIZE + 1) * 4)   // rowptr
                + pad16((size_t)N * 4)                 // dinv
                + 2 * pad16((size_t)N * 8)             // pA, pB
                + pad16((size_t)N * 4);                // sv
    if (need > ws_size) return;

    char* w = (char*)d_ws;
    size_t off = 0;
    auto carve = [&](size_t bytes) { void* p = w + off; off += (bytes + 15) & ~(size_t)15; return p; };
    int*    packed  = (int*)carve((size_t)E * 4);
    int*    hpart   = (int*)carve((size_t)S * K * 4);
    int*    basep   = (int*)carve((size_t)(K + 1) * 4);
    int*    totals  = (int*)carve((size_t)K * 4);
    int*    packed2 = (int*)carve((size_t)E * 4);
    int*    rowptr  = (int*)carve(((size_t)K * BSIZE + 1) * 4);
    float*  dinv    = (float*)carve((size_t)N * 4);
    float2* pA      = (float2*)carve((size_t)N * 8);
    float2* pB      = (float2*)carve((size_t)N * 8);
    float*  sv      = (float*)carve((size_t)N * 4);

    int NB = (N + BLK - 1) / BLK;
    int GB = (G + BLK - 1) / BLK;
    int WB = (N + 3) / 4;                       // wave-per-node grid
    size_t smemK = (size_t)K * 4;

    // level-1: bucket by dst>>8 (256 slices, 1024-thread blocks)
    k_hist   <<<S, BLK2, smemK, stream>>>(dst, hpart, E, chunk, K);
    k_colscan<<<K, NSLICE, 0, stream>>>(hpart, totals, K);
    k_base   <<<1, SCAN_T, 0, stream>>>(totals, basep, K);
    k_scatter<<<S, BLK2, 0, stream>>>(src, dst, hpart, basep, packed, E, chunk, K, sbits);

    // level-2: LDS-staged per-bucket sort -> CSR (rowptr side-output)
    k_sort2  <<<K, S2BLK, (size_t)S2CAP * 4, stream>>>(packed, basep, packed2, rowptr,
                                                       sbits, K, E);

    // dinv + p1
    k_node1  <<<NB, BLK, 0, stream>>>(rowptr, x, W1, dinv, pA, N);

    // fused layers (agg + relu + next matmul)
    k_agg4   <<<WB, BLK, 0, stream>>>(packed2, rowptr, dinv, pA, b1, W2, pB, N, smask);
    k_agg4   <<<WB, BLK, 0, stream>>>(packed2, rowptr, dinv, pB, b2, W3, pA, N, smask);
    k_agg4f  <<<WB, BLK, 0, stream>>>(packed2, rowptr, dinv, pA, b3, Wr, sv, N, smask);

    // pool + readout
    k_out_init<<<GB, BLK, 0, stream>>>(out, br, G);
    k_pool    <<<NB, BLK, 0, stream>>>(sv, batch, out, N);
}